// Round 11
// baseline (168.730 us; speedup 1.0000x reference)
//
#include <hip/hip_runtime.h>

// ContrastiveCosineLoss: mean over i<j of (cos_full - cos_red)^2.
// v6: ONE dispatch. Fused megakernel: blocks 0..255 normalize 8 rows each
// (A_i = [fn_i, rn_i] bf16, K=1152), publish per-group MAGIC flags
// (device-scope); every block then runs the R7-proven 128x64 GEMM after
// spinning on just the 24 flags covering its rows (fine-grained dependency,
// norm tail overlaps gemm start). All 272 blocks co-resident (49KB LDS ->
// 3 blocks/CU) => spin cannot deadlock. d_out zeroed via atomicExch + flag.

#define NROWS 2048
#define KFULL 1024
#define KRED  128
#define KTOT  1152
#define BK    64
#define NT    (KTOT / BK)            // 18 K-tiles
#define NEG_T (KFULL / BK)           // tiles >= 16: negated reduced block
#define CT    32                     // 64-col tiles
#define NBLK  272                    // sum over bi of (32 - 2*bi)
#define NGRP  256                    // 8-row groups
#define INV_PAIRS (1.0f / 2096128.0f)
#define MAGIC 0x13579BDFu            // != 0xAAAAAAAA poison

typedef __attribute__((ext_vector_type(8))) short bf16x8;
typedef __attribute__((ext_vector_type(4))) float f32x4;

__device__ inline unsigned short f2bf(float f) {
  unsigned int u = __float_as_uint(f);
  u += 0x7FFFu + ((u >> 16) & 1u);   // RNE
  return (unsigned short)(u >> 16);
}

// ws layout: uint flags[256] @ 0; uint outflag @ 1024; A (2048x1152 bf16) @ 16384.

__global__ __launch_bounds__(512) void fused_kernel(
    const float* __restrict__ red, const float* __restrict__ full,
    unsigned short* __restrict__ A, unsigned int* __restrict__ flags,
    unsigned int* __restrict__ outflag, float* __restrict__ out)
{
  __shared__ __align__(16) unsigned short ldsA[2][128 * 64];  // 32 KB
  __shared__ __align__(16) unsigned short ldsB[2][64 * 64];   // 16 KB
  __shared__ float redbuf[8];

  const int tid = threadIdx.x;
  const int lane = tid & 63;
  const int wv = tid >> 6;           // 0..7
  const int b = blockIdx.x;

  // ---------- Phase A: normalize (blocks 0..255, one row per wave) ----------
  if (b < NGRP) {
    if (b == 0 && tid == 0) atomicExch(out, 0.0f);   // coherent-point zero

    const int r = b * 8 + wv;
    const float4* fr_ = (const float4*)(full + (size_t)r * KFULL);
    float4 v[4];
    #pragma unroll
    for (int c = 0; c < 4; ++c) v[c] = fr_[c * 64 + lane];
    const float2 u = ((const float2*)(red + (size_t)r * KRED))[lane];

    float ss = 0.f;
    #pragma unroll
    for (int c = 0; c < 4; ++c)
      ss += v[c].x * v[c].x + v[c].y * v[c].y + v[c].z * v[c].z + v[c].w * v[c].w;
    float ss2 = u.x * u.x + u.y * u.y;
    #pragma unroll
    for (int o = 1; o < 64; o <<= 1) {
      ss  += __shfl_xor(ss,  o, 64);
      ss2 += __shfl_xor(ss2, o, 64);
    }
    const float inv  = 1.0f / fmaxf(sqrtf(ss),  1e-8f);
    const float inv2 = 1.0f / fmaxf(sqrtf(ss2), 1e-8f);

    unsigned short* Ar = A + (size_t)r * KTOT;
    #pragma unroll
    for (int c = 0; c < 4; ++c) {
      ushort4 w;
      w.x = f2bf(v[c].x * inv); w.y = f2bf(v[c].y * inv);
      w.z = f2bf(v[c].z * inv); w.w = f2bf(v[c].w * inv);
      ((ushort4*)Ar)[c * 64 + lane] = w;
    }
    ushort2 w2;
    w2.x = f2bf(u.x * inv2); w2.y = f2bf(u.y * inv2);
    ((ushort2*)(Ar + KFULL))[lane] = w2;

    __threadfence();                 // flush this thread's A-writes device-wide
    __syncthreads();                 // all 8 rows flushed
    if (tid == 0) {
      atomicExch(&flags[b], MAGIC);  // release group b
      if (b == 0) atomicExch(outflag, MAGIC);
    }
  }

  // ---------- Phase B: 128x64 GEMM (R7-proven), gated per-row-group ----------
  // XCD-bijective swizzle (272 = 8 XCDs * 34)
  const int swz = (b & 7) * 34 + (b >> 3);
  int rem = swz, bi = 0;
  while (rem >= CT - 2 * bi) { rem -= CT - 2 * bi; ++bi; }
  const int bj = 2 * bi + rem;       // 2*bi .. 31

  // wait for the 16 A-groups (rows bi*128..+127) and 8 B-groups (bj*64..+63)
  if (tid < 24) {
    const int g = (tid < 16) ? (bi * 16 + tid) : (bj * 8 + (tid - 16));
    while (__hip_atomic_load(&flags[g], __ATOMIC_ACQUIRE,
                             __HIP_MEMORY_SCOPE_AGENT) != MAGIC)
      __builtin_amdgcn_s_sleep(1);
  }
  __syncthreads();
  __threadfence();                   // acquire-side fence for all threads

  const int sr = tid >> 3;           // 0..63
  const int ssl = tid & 7;
  const unsigned short* pA = A + (size_t)(bi * 128 + sr) * KTOT + ssl * 8;
  const unsigned short* pB = A + (size_t)(bj * 64 + sr) * KTOT + ssl * 8;
  const int swA0 = sr * 64 + ((ssl ^ (sr & 7)) << 3);          // XOR-swizzled
  const int swA1 = (sr + 64) * 64 + ((ssl ^ (sr & 7)) << 3);   // same row&7
  const int swB  = sr * 64 + ((ssl ^ (sr & 7)) << 3);

  uint4 ra0, ra1, rb;
  auto load_regs = [&](int t) {
    const size_t ko = (size_t)t * BK;
    ra0 = *(const uint4*)(pA + ko);
    ra1 = *(const uint4*)(pA + ko + (size_t)64 * KTOT);
    rb  = *(const uint4*)(pB + ko);
    if (t >= NEG_T) {  // reduced block: B = -A (bf16 sign-bit flip)
      rb.x ^= 0x80008000u; rb.y ^= 0x80008000u;
      rb.z ^= 0x80008000u; rb.w ^= 0x80008000u;
    }
  };
  auto store_lds = [&](int bb) {
    *(uint4*)&ldsA[bb][swA0] = ra0;
    *(uint4*)&ldsA[bb][swA1] = ra1;
    *(uint4*)&ldsB[bb][swB]  = rb;
  };

  const int wr = wv >> 1;            // 0..3 : 32-row band
  const int wc = wv & 1;             // 0..1 : 32-col band
  const int fr = lane & 15;
  const int fs = lane >> 4;          // 0..3
  const int rx = fr & 7;             // swizzle key of frag rows

  f32x4 acc[2][2];
  #pragma unroll
  for (int m = 0; m < 2; ++m)
    #pragma unroll
    for (int n = 0; n < 2; ++n)
      acc[m][n] = (f32x4){0.f, 0.f, 0.f, 0.f};

  load_regs(0);
  store_lds(0);

  for (int t = 0; t < NT; ++t) {
    __syncthreads();                 // buf[t&1] staged & prior reads done
    const bool pf = (t + 1 < NT);
    if (pf) load_regs(t + 1);        // issue early: lands under compute

    const int bb = t & 1;
    #pragma unroll
    for (int kk = 0; kk < 2; ++kk) {
      const int sl = ((kk * 4 + fs) ^ rx) << 3;   // swizzled 16B slot
      bf16x8 af[2], bf[2];
      #pragma unroll
      for (int m = 0; m < 2; ++m)
        af[m] = *(const bf16x8*)&ldsA[bb][(wr * 32 + m * 16 + fr) * 64 + sl];
      #pragma unroll
      for (int n = 0; n < 2; ++n)
        bf[n] = *(const bf16x8*)&ldsB[bb][(wc * 32 + n * 16 + fr) * 64 + sl];
      #pragma unroll
      for (int m = 0; m < 2; ++m)
        #pragma unroll
        for (int n = 0; n < 2; ++n)
          acc[m][n] = __builtin_amdgcn_mfma_f32_16x16x32_bf16(
              af[m], bf[n], acc[m][n], 0, 0, 0);
    }
    if (pf) store_lds((t + 1) & 1);  // other buffer: safe without barrier
  }

  // epilogue: sum d^2 over strict upper triangle (gj > gi)
  float s = 0.f;
  #pragma unroll
  for (int m = 0; m < 2; ++m) {
    const int gi0 = bi * 128 + wr * 32 + m * 16 + fs * 4;
    #pragma unroll
    for (int n = 0; n < 2; ++n) {
      const int gj = bj * 64 + wc * 32 + n * 16 + fr;
      #pragma unroll
      for (int j = 0; j < 4; ++j) {
        if (gj > gi0 + j) {
          const float d = acc[m][n][j];
          s += d * d;
        }
      }
    }
  }
  #pragma unroll
  for (int o = 32; o > 0; o >>= 1) s += __shfl_down(s, o, 64);
  if (lane == 0) redbuf[wv] = s;
  __syncthreads();

  if (tid == 0) {
    float tot = 0.f;
    #pragma unroll
    for (int w = 0; w < 8; ++w) tot += redbuf[w];
    while (__hip_atomic_load(outflag, __ATOMIC_ACQUIRE,
                             __HIP_MEMORY_SCOPE_AGENT) != MAGIC)
      __builtin_amdgcn_s_sleep(1);   // set ~10 us ago; effectively instant
    atomicAdd(out, tot * INV_PAIRS);
  }
}

extern "C" void kernel_launch(void* const* d_in, const int* in_sizes, int n_in,
                              void* d_out, int out_size, void* d_ws, size_t ws_size,
                              hipStream_t stream)
{
  const float* red  = (const float*)d_in[0];   // (2048, 128) f32
  const float* full = (const float*)d_in[1];   // (2048, 1024) f32
  unsigned int* flags = (unsigned int*)d_ws;   // 256 group flags (poison != MAGIC)
  unsigned int* outflag = flags + NGRP;
  unsigned short* A = (unsigned short*)((char*)d_ws + 16384);  // 2048x1152 bf16

  fused_kernel<<<NBLK, 512, 0, stream>>>(red, full, A, flags, outflag, (float*)d_out);
}

// Round 12
// 80.668 us; speedup vs baseline: 2.0917x; 2.0917x over previous
//
#include <hip/hip_runtime.h>

// ContrastiveCosineLoss: mean over i<j of (cos_full - cos_red)^2.
// v7 = R7 (best, 80.8us) + depth-3 register prefetch in the K-loop.
// ONE GEMM: A_i = [fn_i, rn_i], B_j = [fn_j, -rn_j] (bf16, K=1152),
// 128x64 tiles, 272 blocks, 8 waves. At iter t: store tile t+1 (loads
// issued 2 barriers earlier -> full latency hidden), issue loads t+3,
// compute tile t. Two LDS buffers, 1 barrier/tile. Named register sets
// (compile-time indexed; no scratch). 2 dispatches, spread atomics.

#define NROWS 2048
#define KFULL 1024
#define KRED  128
#define KTOT  1152
#define BK    64
#define NT    (KTOT / BK)            // 18 K-tiles
#define NEG_T (KFULL / BK)           // tiles >= 16: negated reduced block
#define CT    32                     // 64-col tiles
#define NBLK  272                    // sum over bi of (32 - 2*bi)
#define INV_PAIRS (1.0f / 2096128.0f)
#define NSLOT 64

typedef __attribute__((ext_vector_type(8))) short bf16x8;
typedef __attribute__((ext_vector_type(4))) float f32x4;

__device__ inline unsigned short f2bf(float f) {
  unsigned int u = __float_as_uint(f);
  u += 0x7FFFu + ((u >> 16) & 1u);   // RNE
  return (unsigned short)(u >> 16);
}

// ws layout: float slots [0..64*32) (128 B apart); uint done @ float idx 2048;
// A (2048x1152 bf16) @ byte 16384.

// One WAVE per row: normalize full (1024) and reduced (128), write bf16 row.
__global__ __launch_bounds__(256) void norm_kernel(
    const float* __restrict__ red, const float* __restrict__ full,
    unsigned short* __restrict__ A, float* __restrict__ ws_part,
    unsigned int* __restrict__ ws_done)
{
  const int tid = threadIdx.x;
  if (blockIdx.x == 0) {             // zero reduction state for pair_gemm
    if (tid < NSLOT) ws_part[tid * 32] = 0.0f;
    if (tid == NSLOT) *ws_done = 0u;
  }
  const int lane = tid & 63;
  const int r = blockIdx.x * 4 + (tid >> 6);

  const float4* fr_ = (const float4*)(full + (size_t)r * KFULL);
  float4 v[4];
  #pragma unroll
  for (int c = 0; c < 4; ++c) v[c] = fr_[c * 64 + lane];
  const float2 u = ((const float2*)(red + (size_t)r * KRED))[lane];

  float ss = 0.f;
  #pragma unroll
  for (int c = 0; c < 4; ++c)
    ss += v[c].x * v[c].x + v[c].y * v[c].y + v[c].z * v[c].z + v[c].w * v[c].w;
  float ss2 = u.x * u.x + u.y * u.y;
  #pragma unroll
  for (int o = 1; o < 64; o <<= 1) {       // fused butterfly reduce
    ss  += __shfl_xor(ss,  o, 64);
    ss2 += __shfl_xor(ss2, o, 64);
  }
  const float inv  = 1.0f / fmaxf(sqrtf(ss),  1e-8f);
  const float inv2 = 1.0f / fmaxf(sqrtf(ss2), 1e-8f);

  unsigned short* Ar = A + (size_t)r * KTOT;
  #pragma unroll
  for (int c = 0; c < 4; ++c) {
    ushort4 w;
    w.x = f2bf(v[c].x * inv); w.y = f2bf(v[c].y * inv);
    w.z = f2bf(v[c].z * inv); w.w = f2bf(v[c].w * inv);
    ((ushort4*)Ar)[c * 64 + lane] = w;
  }
  ushort2 w2;
  w2.x = f2bf(u.x * inv2); w2.y = f2bf(u.y * inv2);
  ((ushort2*)(Ar + KFULL))[lane] = w2;
}

// 128x64 tile, 8 waves (4x2), wave tile 32x32 (2x2 frags of 16x16x32).
__global__ __launch_bounds__(512) void pair_gemm(
    const unsigned short* __restrict__ A, float* __restrict__ ws_part,
    unsigned int* __restrict__ ws_done, float* __restrict__ out)
{
  __shared__ __align__(16) unsigned short ldsA[2][128 * 64];  // 32 KB
  __shared__ __align__(16) unsigned short ldsB[2][64 * 64];   // 16 KB
  __shared__ float redbuf[8];
  __shared__ int islast;

  const int tid = threadIdx.x;

  // XCD-bijective swizzle (272 = 8 XCDs * 34)
  const int swz = (blockIdx.x & 7) * 34 + (blockIdx.x >> 3);
  int rem = swz, bi = 0;
  while (rem >= CT - 2 * bi) { rem -= CT - 2 * bi; ++bi; }
  const int bj = 2 * bi + rem;       // 2*bi .. 31

  // staging: thread t -> (row = t>>3, 16B slot = t&7); A covers rows sr and
  // sr+64 (two loads), B covers row sr (one load).
  const int sr = tid >> 3;           // 0..63
  const int ssl = tid & 7;
  const unsigned short* pA = A + (size_t)(bi * 128 + sr) * KTOT + ssl * 8;
  const unsigned short* pB = A + (size_t)(bj * 64 + sr) * KTOT + ssl * 8;
  const int swA0 = sr * 64 + ((ssl ^ (sr & 7)) << 3);          // XOR-swizzled
  const int swA1 = (sr + 64) * 64 + ((ssl ^ (sr & 7)) << 3);   // same row&7
  const int swB  = sr * 64 + ((ssl ^ (sr & 7)) << 3);

  // two NAMED register sets (depth-3 pipeline; compile-time indexed)
  uint4 a0A, a1A, bA;                // set A (odd tiles)
  uint4 a0B, a1B, bB;                // set B (even tiles)

  auto loadT = [&](uint4& x, uint4& y, uint4& z, int t) {
    const size_t ko = (size_t)t * BK;
    x = *(const uint4*)(pA + ko);
    y = *(const uint4*)(pA + ko + (size_t)64 * KTOT);
    z = *(const uint4*)(pB + ko);
    if (t >= NEG_T) {                // reduced block: B = -A (sign-bit flip)
      z.x ^= 0x80008000u; z.y ^= 0x80008000u;
      z.z ^= 0x80008000u; z.w ^= 0x80008000u;
    }
  };
  auto storeT = [&](const uint4& x, const uint4& y, const uint4& z, int bb) {
    *(uint4*)&ldsA[bb][swA0] = x;
    *(uint4*)&ldsA[bb][swA1] = y;
    *(uint4*)&ldsB[bb][swB]  = z;
  };

  const int lane = tid & 63;
  const int wv = tid >> 6;           // 0..7
  const int wr = wv >> 1;            // 0..3 : 32-row band
  const int wc = wv & 1;             // 0..1 : 32-col band
  const int fr = lane & 15;
  const int fs = lane >> 4;          // 0..3
  const int rx = fr & 7;             // swizzle key of frag rows

  f32x4 acc[2][2];
  #pragma unroll
  for (int m = 0; m < 2; ++m)
    #pragma unroll
    for (int n = 0; n < 2; ++n)
      acc[m][n] = (f32x4){0.f, 0.f, 0.f, 0.f};

  auto compute = [&](int bb) {
    #pragma unroll
    for (int kk = 0; kk < 2; ++kk) {
      const int sl = ((kk * 4 + fs) ^ rx) << 3;   // swizzled 16B slot
      bf16x8 af[2], bf[2];
      #pragma unroll
      for (int m = 0; m < 2; ++m)
        af[m] = *(const bf16x8*)&ldsA[bb][(wr * 32 + m * 16 + fr) * 64 + sl];
      #pragma unroll
      for (int n = 0; n < 2; ++n)
        bf[n] = *(const bf16x8*)&ldsB[bb][(wc * 32 + n * 16 + fr) * 64 + sl];
      #pragma unroll
      for (int m = 0; m < 2; ++m)
        #pragma unroll
        for (int n = 0; n < 2; ++n)
          acc[m][n] = __builtin_amdgcn_mfma_f32_16x16x32_bf16(
              af[m], bf[n], acc[m][n], 0, 0, 0);
    }
  };

  // prologue: tile0 -> buf0; preload tile1 (setA), tile2 (setB)
  loadT(a0A, a1A, bA, 0);
  storeT(a0A, a1A, bA, 0);
  loadT(a0A, a1A, bA, 1);
  loadT(a0B, a1B, bB, 2);

  // main loop: 2 tiles per trip, 1 barrier per tile.
  // trip t (even): [bar] store setA(t+1)->buf1, issue setA<-t+3, compute(t,buf0)
  //                [bar] store setB(t+2)->buf0, issue setB<-t+4, compute(t+1,buf1)
  for (int t = 0; t < NT; t += 2) {
    __syncthreads();                 // buf0 holds tile t; buf1 free to write
    storeT(a0A, a1A, bA, 1);         // tile t+1 (loads issued 2 barriers ago)
    if (t + 3 < NT) loadT(a0A, a1A, bA, t + 3);
    compute(0);                      // tile t
    __syncthreads();                 // buf1 holds tile t+1; buf0 free
    if (t + 2 < NT) storeT(a0B, a1B, bB, 0);   // tile t+2
    if (t + 4 < NT) loadT(a0B, a1B, bB, t + 4);
    compute(1);                      // tile t+1
  }

  // epilogue: sum d^2 over strict upper triangle (gj > gi)
  float s = 0.f;
  #pragma unroll
  for (int m = 0; m < 2; ++m) {
    const int gi0 = bi * 128 + wr * 32 + m * 16 + fs * 4;
    #pragma unroll
    for (int n = 0; n < 2; ++n) {
      const int gj = bj * 64 + wc * 32 + n * 16 + fr;
      #pragma unroll
      for (int j = 0; j < 4; ++j) {
        if (gj > gi0 + j) {
          const float d = acc[m][n][j];
          s += d * d;
        }
      }
    }
  }
  #pragma unroll
  for (int o = 32; o > 0; o >>= 1) s += __shfl_down(s, o, 64);
  if (lane == 0) redbuf[wv] = s;
  __syncthreads();

  if (tid == 0) {
    float tot = 0.f;
    #pragma unroll
    for (int w = 0; w < 8; ++w) tot += redbuf[w];
    atomicAdd(&ws_part[(blockIdx.x & (NSLOT - 1)) * 32], tot);
    __threadfence();                                 // release slots
    const unsigned int old = atomicAdd(ws_done, 1u);
    islast = (old == NBLK - 1) ? 1 : 0;
  }
  __syncthreads();

  if (islast && tid < NSLOT) {       // last block finalizes (no extra dispatch)
    float v = atomicAdd(&ws_part[tid * 32], 0.0f);   // device-scope read
    #pragma unroll
    for (int o = 32; o > 0; o >>= 1) v += __shfl_down(v, o, 64);
    if (tid == 0) out[0] = v * INV_PAIRS;
  }
}

extern "C" void kernel_launch(void* const* d_in, const int* in_sizes, int n_in,
                              void* d_out, int out_size, void* d_ws, size_t ws_size,
                              hipStream_t stream)
{
  const float* red  = (const float*)d_in[0];   // (2048, 128) f32
  const float* full = (const float*)d_in[1];   // (2048, 1024) f32
  float* ws_part = (float*)d_ws;
  unsigned int* ws_done = (unsigned int*)d_ws + 2048;
  unsigned short* A = (unsigned short*)((char*)d_ws + 16384);  // 2048x1152 bf16

  norm_kernel<<<NROWS / 4, 256, 0, stream>>>(red, full, A, ws_part, ws_done);
  pair_gemm<<<NBLK, 512, 0, stream>>>(A, ws_part, ws_done, (float*)d_out);
}